// Round 4
// baseline (135.487 us; speedup 1.0000x reference)
//
#include <hip/hip_runtime.h>
#include <math.h>

#define N_FRAMES 20000
#define N_BEADS  50
#define N_DIST   1225   // sum_{inc=1}^{49} (50-inc)
#define N_ANG    48
#define N_DIH    47
#define OUT_STRIDE (N_DIST + N_ANG + 2 * N_DIH)  // 1367 floats = 5468 B (== 12 mod 16!)
#define FPB      8              // frames per block; 20000/8 = 2500 blocks
#define HALF     4              // output staged+copied 4 frames at a time
#define FRAME_F  (N_BEADS * 3)  // 150 packed floats per frame (global)
#define FRAME_P  (N_BEADS * 4)  // 200 padded floats per frame (LDS, float4/bead)

// cumulative pair count before separation `inc`:
// cum(inc) = sum_{k=1}^{inc-1} (50-k) = (inc-1)*50 - (inc-1)*inc/2
__device__ __forceinline__ int cum_pairs(int inc) {
    return (inc - 1) * 50 - ((inc - 1) * inc) / 2;
}

// Fast HW approx ops (single instruction, ~1 ulp rel err ~2^-22).
__device__ __forceinline__ float fsqrt_fast(float x) { return __builtin_amdgcn_sqrtf(x); }
__device__ __forceinline__ float frsq_fast(float x)  { return __builtin_amdgcn_rsqf(x); }

// R4 DIAGNOSTIC ROUND: identical to R3 except copy-out is repeated 3x
// (idempotent; asm memory clobber blocks dead-store elimination).
// Purpose: 3 structurally different kernels (R0-R3) all land at ~58-59us
// while every pipe models out at <20us, and the kernel's own rocprof row
// is hidden below the ~65us harness fills. Tripling the writes either
// (a) adds ~+100us -> store-path is the real limit AND the kernel row
// surfaces with FETCH/WRITE/Occupancy visible (FETCH~=WRITE => RFO), or
// (b) adds ~+3us -> store path exonerated; bottleneck is serial/fixed
// structure -> next round: persistent blocks + pipelining.
__global__ __launch_bounds__(256, 5)
void protein_feat_kernel(const float* __restrict__ data, float* __restrict__ out) {
    const int tid = threadIdx.x;
    const int f0  = blockIdx.x * FPB;

    __shared__ __align__(16) float s[FPB * FRAME_P];        // 6.4 KB input, float4/bead
    __shared__ __align__(16) float sout[HALF * OUT_STRIDE]; // 21.9 KB staged output

    // ---- stage input: issue global loads first, overlap index math ----
    const float4* g4 = (const float4*)(data + (size_t)f0 * FRAME_F);
    float4 v0 = g4[tid];                      // 300 float4s total; tid<256 always valid
    const bool h2 = (tid + 256) < (FPB * FRAME_F / 4);
    float4 v1;
    if (h2) v1 = g4[tid + 256];

    // frame-independent pair bead-indices (overlaps the vmem latency)
    int bi_idx[5], bj_idx[5];
#pragma unroll
    for (int k = 0; k < 5; ++k) {
        int p = tid + k * 256;
        if (p < N_DIST) {
            float disc = 9801.0f - 8.0f * (float)p;
            int inc = (int)((101.0f - sqrtf(disc)) * 0.5f);
            inc = min(max(inc, 1), 49);
            while (inc < 49 && cum_pairs(inc + 1) <= p) ++inc;  // float-rounding fixup
            while (inc > 1  && cum_pairs(inc)     >  p) --inc;
            int i = p - cum_pairs(inc);
            bi_idx[k] = i;
            bj_idx[k] = i + inc;
        } else {
            bi_idx[k] = 0; bj_idx[k] = 0;
        }
    }
    const bool has_tail = (1024 + tid) < N_DIST;  // tid < 201

    // repack packed(xyz) -> padded(float4/bead) into LDS
    {
        int gi = 4 * tid;
#pragma unroll
        for (int c = 0; c < 4; ++c) {
            int B  = (gi + c) / 3;
            int cc = (gi + c) - 3 * B;
            s[B * 4 + cc] = (&v0.x)[c];
        }
        if (h2) {
            int gj = 4 * (tid + 256);
#pragma unroll
            for (int c = 0; c < 4; ++c) {
                int B  = (gj + c) / 3;
                int cc = (gj + c) - 3 * B;
                s[B * 4 + cc] = (&v1.x)[c];
            }
        }
    }
    __syncthreads();

#pragma unroll 1
    for (int half = 0; half < 2; ++half) {
        const int fbase = half * HALF;  // first frame of this half (block-local)

        // ---- distances: 4 frames, 5 pairs/thread, writes to LDS ----
#pragma unroll 1
        for (int fl = 0; fl < HALF; ++fl) {
            const float4* sf4 = (const float4*)s + (fbase + fl) * N_BEADS;
            float* fo = sout + fl * OUT_STRIDE;
#pragma unroll
            for (int k = 0; k < 4; ++k) {   // p = tid + k*256 < 1024 always valid
                float4 bi = sf4[bi_idx[k]];
                float4 bj = sf4[bj_idx[k]];
                float dx = bj.x - bi.x;
                float dy = bj.y - bi.y;
                float dz = bj.z - bi.z;
                fo[tid + k * 256] = fsqrt_fast(dx * dx + dy * dy + dz * dz);
            }
            if (has_tail) {
                float4 bi = sf4[bi_idx[4]];
                float4 bj = sf4[bj_idx[4]];
                float dx = bj.x - bi.x;
                float dy = bj.y - bi.y;
                float dz = bj.z - bi.z;
                fo[tid + 1024] = fsqrt_fast(dx * dx + dy * dy + dz * dz);
            }
        }

        // ---- angles: 4 frames x 48 = 192 items (single pass, tid < 192) ----
        if (tid < HALF * N_ANG) {
            int fl = tid / N_ANG;
            int a  = tid - fl * N_ANG;
            const float4* sf4 = (const float4*)s + (fbase + fl) * N_BEADS;
            float4 A = sf4[a], B = sf4[a + 1], C = sf4[a + 2];
            float b1x = A.x - B.x, b1y = A.y - B.y, b1z = A.z - B.z;
            float b2x = C.x - B.x, b2y = C.y - B.y, b2z = C.z - B.z;
            float dot = b1x * b2x + b1y * b2y + b1z * b2z;
            float s1 = b1x * b1x + b1y * b1y + b1z * b1z;
            float s2 = b2x * b2x + b2y * b2y + b2z * b2z;
            float c = dot * frsq_fast(s1 * s2);
            c = fminf(1.0f, fmaxf(-1.0f, c));
            sout[fl * OUT_STRIDE + N_DIST + a] = acosf(c);
        }

        // ---- dihedrals: 4 frames x 47 = 188 items (single pass, tid < 188) ----
        if (tid < HALF * N_DIH) {
            int fl = tid / N_DIH;
            int d  = tid - fl * N_DIH;
            const float4* sf4 = (const float4*)s + (fbase + fl) * N_BEADS;
            float4 P0 = sf4[d], P1 = sf4[d + 1], P2 = sf4[d + 2], P3 = sf4[d + 3];

            float ax = P1.x - P0.x, ay = P1.y - P0.y, az = P1.z - P0.z;
            float bx = P2.x - P1.x, by = P2.y - P1.y, bz = P2.z - P1.z;
            float cx = P3.x - P2.x, cy = P3.y - P2.y, cz = P3.z - P2.z;

            float p1x = ay * bz - az * by;
            float p1y = az * bx - ax * bz;
            float p1z = ax * by - ay * bx;
            float p2x = by * cz - bz * cy;
            float p2y = bz * cx - bx * cz;
            float p2z = bx * cy - by * cx;

            float s1 = p1x * p1x + p1y * p1y + p1z * p1z;
            float s2 = p2x * p2x + p2y * p2y + p2z * p2z;
            float sb = bx * bx + by * by + bz * bz;

            float dotp = p1x * p2x + p1y * p2y + p1z * p2z;
            float qx = p1y * p2z - p1z * p2y;
            float qy = p1z * p2x - p1x * p2z;
            float qz = p1x * p2y - p1y * p2x;
            float trip = qx * bx + qy * by + qz * bz;

            float inv12 = frsq_fast(s1 * s2);
            float invb  = frsq_fast(sb);
            float* base = sout + fl * OUT_STRIDE + N_DIST + N_ANG;
            base[d]         = dotp * inv12;
            base[N_DIH + d] = trip * inv12 * invb;
        }

        __syncthreads();  // sout fully written

        // ---- DIAGNOSTIC: copy-out repeated 3x (idempotent, same bytes) ----
        // Pass 0/1 are extra store traffic; pass 2 is the real write. The asm
        // memory clobber prevents the compiler from eliminating earlier passes.
#pragma unroll 1
        for (int pass = 0; pass < 3; ++pass) {
            const float4* src4 = (const float4*)sout;
            float4* dst4 = (float4*)(out + (size_t)(f0 + fbase) * OUT_STRIDE);
#pragma unroll 1
            for (int x = tid; x < HALF * OUT_STRIDE / 4; x += 256) {  // 1367 float4s
                dst4[x] = src4[x];
            }
            __asm__ volatile("" ::: "memory");  // no dead-store elim between passes
        }

        __syncthreads();  // protect sout before half 1 overwrites it
    }
}

extern "C" void kernel_launch(void* const* d_in, const int* in_sizes, int n_in,
                              void* d_out, int out_size, void* d_ws, size_t ws_size,
                              hipStream_t stream) {
    const float* data = (const float*)d_in[0];
    float* out = (float*)d_out;
    protein_feat_kernel<<<N_FRAMES / FPB, 256, 0, stream>>>(data, out);
}

// Round 6
// 132.553 us; speedup vs baseline: 1.0221x; 1.0221x over previous
//
#include <hip/hip_runtime.h>
#include <math.h>

#define N_FRAMES 20000
#define N_BEADS  50
#define N_DIST   1225   // sum_{inc=1}^{49} (50-inc)
#define N_ANG    48
#define N_DIH    47
#define OUT_STRIDE (N_DIST + N_ANG + 2 * N_DIH)  // 1367 floats = 5468 B (== 12 mod 16!)
#define FPB      8              // frames per block; 20000/8 = 2500 blocks
#define HALF     4              // output staged+copied 4 frames at a time
#define FRAME_F  (N_BEADS * 3)  // 150 packed floats per frame (global)
#define FRAME_P  (N_BEADS * 4)  // 200 padded floats per frame (LDS, float4/bead)

// true clang vector type: __builtin_nontemporal_store requires a vector of
// scalars, not HIP_vector_type's struct wrapper (R5 compile failure).
typedef float f32x4 __attribute__((ext_vector_type(4)));

// cumulative pair count before separation `inc`:
// cum(inc) = sum_{k=1}^{inc-1} (50-k) = (inc-1)*50 - (inc-1)*inc/2
__device__ __forceinline__ int cum_pairs(int inc) {
    return (inc - 1) * 50 - ((inc - 1) * inc) / 2;
}

// Fast HW approx ops (single instruction, ~1 ulp rel err ~2^-22).
__device__ __forceinline__ float fsqrt_fast(float x) { return __builtin_amdgcn_sqrtf(x); }
__device__ __forceinline__ float frsq_fast(float x)  { return __builtin_amdgcn_rsqf(x); }

// R5 (resubmit): R3 structure + NON-TEMPORAL copy-out (single variable).
// Evidence trail: R4 showed repeat store passes run at ~19 TB/s (L2-hit)
// while the first-touch pass + rest of kernel costs ~58us at ~2 TB/s.
// WRITE_SIZE is a TCC(L2) counter, so the 437MB harness fill lands in the
// 256MB L3 as dirty poison that is still draining L3->HBM when our kernel
// runs; our first-touch store allocations each force a dirty-line eviction
// -> store stream serializes behind the drain. nt stores bypass L2/L3
// allocation (fire-and-forget to HBM write queue), decoupling us from the
// drain. Predict: dur 124 -> ~90-100 if eviction-serialization is the
// bottleneck; unchanged -> harness-drain floor (ROOFLINE next round);
// regression -> in-cache poison-overwrite was saving traffic (revert).
__global__ __launch_bounds__(256, 5)
void protein_feat_kernel(const float* __restrict__ data, float* __restrict__ out) {
    const int tid = threadIdx.x;
    const int f0  = blockIdx.x * FPB;

    __shared__ __align__(16) float s[FPB * FRAME_P];        // 6.4 KB input, float4/bead
    __shared__ __align__(16) float sout[HALF * OUT_STRIDE]; // 21.9 KB staged output

    // ---- stage input: issue global loads first, overlap index math ----
    const float4* g4 = (const float4*)(data + (size_t)f0 * FRAME_F);
    float4 v0 = g4[tid];                      // 300 float4s total; tid<256 always valid
    const bool h2 = (tid + 256) < (FPB * FRAME_F / 4);
    float4 v1;
    if (h2) v1 = g4[tid + 256];

    // frame-independent pair bead-indices (overlaps the vmem latency)
    int bi_idx[5], bj_idx[5];
#pragma unroll
    for (int k = 0; k < 5; ++k) {
        int p = tid + k * 256;
        if (p < N_DIST) {
            float disc = 9801.0f - 8.0f * (float)p;
            int inc = (int)((101.0f - sqrtf(disc)) * 0.5f);
            inc = min(max(inc, 1), 49);
            while (inc < 49 && cum_pairs(inc + 1) <= p) ++inc;  // float-rounding fixup
            while (inc > 1  && cum_pairs(inc)     >  p) --inc;
            int i = p - cum_pairs(inc);
            bi_idx[k] = i;
            bj_idx[k] = i + inc;
        } else {
            bi_idx[k] = 0; bj_idx[k] = 0;
        }
    }
    const bool has_tail = (1024 + tid) < N_DIST;  // tid < 201

    // repack packed(xyz) -> padded(float4/bead) into LDS
    {
        int gi = 4 * tid;
#pragma unroll
        for (int c = 0; c < 4; ++c) {
            int B  = (gi + c) / 3;
            int cc = (gi + c) - 3 * B;
            s[B * 4 + cc] = (&v0.x)[c];
        }
        if (h2) {
            int gj = 4 * (tid + 256);
#pragma unroll
            for (int c = 0; c < 4; ++c) {
                int B  = (gj + c) / 3;
                int cc = (gj + c) - 3 * B;
                s[B * 4 + cc] = (&v1.x)[c];
            }
        }
    }
    __syncthreads();

#pragma unroll 1
    for (int half = 0; half < 2; ++half) {
        const int fbase = half * HALF;  // first frame of this half (block-local)

        // ---- distances: 4 frames, 5 pairs/thread, writes to LDS ----
#pragma unroll 1
        for (int fl = 0; fl < HALF; ++fl) {
            const float4* sf4 = (const float4*)s + (fbase + fl) * N_BEADS;
            float* fo = sout + fl * OUT_STRIDE;
#pragma unroll
            for (int k = 0; k < 4; ++k) {   // p = tid + k*256 < 1024 always valid
                float4 bi = sf4[bi_idx[k]];
                float4 bj = sf4[bj_idx[k]];
                float dx = bj.x - bi.x;
                float dy = bj.y - bi.y;
                float dz = bj.z - bi.z;
                fo[tid + k * 256] = fsqrt_fast(dx * dx + dy * dy + dz * dz);
            }
            if (has_tail) {
                float4 bi = sf4[bi_idx[4]];
                float4 bj = sf4[bj_idx[4]];
                float dx = bj.x - bi.x;
                float dy = bj.y - bi.y;
                float dz = bj.z - bi.z;
                fo[tid + 1024] = fsqrt_fast(dx * dx + dy * dy + dz * dz);
            }
        }

        // ---- angles: 4 frames x 48 = 192 items (single pass, tid < 192) ----
        if (tid < HALF * N_ANG) {
            int fl = tid / N_ANG;
            int a  = tid - fl * N_ANG;
            const float4* sf4 = (const float4*)s + (fbase + fl) * N_BEADS;
            float4 A = sf4[a], B = sf4[a + 1], C = sf4[a + 2];
            float b1x = A.x - B.x, b1y = A.y - B.y, b1z = A.z - B.z;
            float b2x = C.x - B.x, b2y = C.y - B.y, b2z = C.z - B.z;
            float dot = b1x * b2x + b1y * b2y + b1z * b2z;
            float s1 = b1x * b1x + b1y * b1y + b1z * b1z;
            float s2 = b2x * b2x + b2y * b2y + b2z * b2z;
            float c = dot * frsq_fast(s1 * s2);
            c = fminf(1.0f, fmaxf(-1.0f, c));
            sout[fl * OUT_STRIDE + N_DIST + a] = acosf(c);
        }

        // ---- dihedrals: 4 frames x 47 = 188 items (single pass, tid < 188) ----
        if (tid < HALF * N_DIH) {
            int fl = tid / N_DIH;
            int d  = tid - fl * N_DIH;
            const float4* sf4 = (const float4*)s + (fbase + fl) * N_BEADS;
            float4 P0 = sf4[d], P1 = sf4[d + 1], P2 = sf4[d + 2], P3 = sf4[d + 3];

            float ax = P1.x - P0.x, ay = P1.y - P0.y, az = P1.z - P0.z;
            float bx = P2.x - P1.x, by = P2.y - P1.y, bz = P2.z - P1.z;
            float cx = P3.x - P2.x, cy = P3.y - P2.y, cz = P3.z - P2.z;

            float p1x = ay * bz - az * by;
            float p1y = az * bx - ax * bz;
            float p1z = ax * by - ay * bx;
            float p2x = by * cz - bz * cy;
            float p2y = bz * cx - bx * cz;
            float p2z = bx * cy - by * cx;

            float s1 = p1x * p1x + p1y * p1y + p1z * p1z;
            float s2 = p2x * p2x + p2y * p2y + p2z * p2z;
            float sb = bx * bx + by * by + bz * bz;

            float dotp = p1x * p2x + p1y * p2y + p1z * p2z;
            float qx = p1y * p2z - p1z * p2y;
            float qy = p1z * p2x - p1x * p2z;
            float qz = p1x * p2y - p1y * p2x;
            float trip = qx * bx + qy * by + qz * bz;

            float inv12 = frsq_fast(s1 * s2);
            float invb  = frsq_fast(sb);
            float* base = sout + fl * OUT_STRIDE + N_DIST + N_ANG;
            base[d]         = dotp * inv12;
            base[N_DIH + d] = trip * inv12 * invb;
        }

        __syncthreads();  // sout fully written

        // ---- bulk copy-out: 4 rows = 21872 B, contiguous & 16B-aligned ----
        // NON-TEMPORAL: bypass L2/L3 allocation; do not join the poison-drain
        // eviction dance. dst byte offset = blk*43744 + half*21872, both /16.
        {
            const f32x4* src4 = (const f32x4*)sout;
            f32x4* dst4 = (f32x4*)(out + (size_t)(f0 + fbase) * OUT_STRIDE);
#pragma unroll 1
            for (int x = tid; x < HALF * OUT_STRIDE / 4; x += 256) {  // 1367 float4s
                __builtin_nontemporal_store(src4[x], &dst4[x]);
            }
        }

        __syncthreads();  // protect sout before half 1 overwrites it
    }
}

extern "C" void kernel_launch(void* const* d_in, const int* in_sizes, int n_in,
                              void* d_out, int out_size, void* d_ws, size_t ws_size,
                              hipStream_t stream) {
    const float* data = (const float*)d_in[0];
    float* out = (float*)d_out;
    protein_feat_kernel<<<N_FRAMES / FPB, 256, 0, stream>>>(data, out);
}

// Round 7
// 123.181 us; speedup vs baseline: 1.0999x; 1.0761x over previous
//
#include <hip/hip_runtime.h>
#include <math.h>

#define N_FRAMES 20000
#define N_BEADS  50
#define N_DIST   1225   // sum_{inc=1}^{49} (50-inc)
#define N_ANG    48
#define N_DIH    47
#define OUT_STRIDE (N_DIST + N_ANG + 2 * N_DIH)  // 1367
#define FPB      8              // frames per block; 20000/8 = 2500 blocks
#define FRAME_F  (N_BEADS * 3)  // 150 packed floats per frame (global)
#define FRAME_P  (N_BEADS * 4)  // 200 padded floats per frame (LDS, float4/bead)

// cumulative pair count before separation `inc`:
// cum(inc) = sum_{k=1}^{inc-1} (50-k) = (inc-1)*50 - (inc-1)*inc/2
__device__ __forceinline__ int cum_pairs(int inc) {
    return (inc - 1) * 50 - ((inc - 1) * inc) / 2;
}

// Fast HW approx ops (single instruction, ~1 ulp rel err ~2^-22).
__device__ __forceinline__ float fsqrt_fast(float x) { return __builtin_amdgcn_sqrtf(x); }
__device__ __forceinline__ float frsq_fast(float x)  { return __builtin_amdgcn_rsqf(x); }

// R7: REVERT to the best measured variant (R2, 123.0us).
// Session model (7 single-variable probes, R0-R6): the timed iteration is
// bound by TOTAL HBM write bytes = harness re-poison fill (437MB, WRITE_SIZE
// proves it leaves L2) + mandatory output (109MB) + input (12MB) through one
// write path. Evidence: (a) 4 structurally different kernels land 123-135;
// (b) repeat stores to resident lines are ~19 TB/s (R4: +218MB -> +11.4us,
// no new HBM bytes); (c) nt stores regress +8.5us (R6: poison-cancellation
// lost, +109MB HBM bytes); (d) fast-math/occupancy/store-coalescing all
// null (no byte change). Cached direct stores maximize in-cache poison
// overwrite (cancellation). Kernel-side levers are exhausted; remaining
// time is harness poison-drain sharing the write path.
__global__ __launch_bounds__(256, 6)
void protein_feat_kernel(const float* __restrict__ data, float* __restrict__ out) {
    const int tid = threadIdx.x;
    const int f0  = blockIdx.x * FPB;

    // padded layout: one float4 per bead -> single ds_read_b128 per bead
    __shared__ __align__(16) float s[FPB * FRAME_P];  // 8 * 200 * 4B = 6.4 KB

    // ---- stage: issue global loads FIRST, overlap index math, then LDS ----
    // FPB*FRAME_F/4 = 300 float4s; thread t owns g4[t] and (t<44) g4[t+256].
    const float4* g4 = (const float4*)(data + (size_t)f0 * FRAME_F);
    float4 v0 = g4[tid];                      // tid < 256 <= 300 always
    const bool h2 = (tid + 256) < (FPB * FRAME_F / 4);
    float4 v1;
    if (h2) v1 = g4[tid + 256];

    // ---- frame-independent pair bead-indices: overlaps the vmem latency ----
    int bi_idx[5], bj_idx[5];
#pragma unroll
    for (int k = 0; k < 5; ++k) {
        int p = tid + k * 256;
        if (p < N_DIST) {
            float disc = 9801.0f - 8.0f * (float)p;
            int inc = (int)((101.0f - sqrtf(disc)) * 0.5f);
            inc = min(max(inc, 1), 49);
            while (inc < 49 && cum_pairs(inc + 1) <= p) ++inc;  // float-rounding fixup
            while (inc > 1  && cum_pairs(inc)     >  p) --inc;
            int i = p - cum_pairs(inc);
            bi_idx[k] = i;
            bj_idx[k] = i + inc;
        } else {
            bi_idx[k] = 0; bj_idx[k] = 0;
        }
    }
    const bool has_tail = (1024 + tid) < N_DIST;  // tid < 201

    // repack packed(xyz) -> padded(float4/bead) into LDS
    {
        int gi = 4 * tid;
#pragma unroll
        for (int c = 0; c < 4; ++c) {
            int B  = (gi + c) / 3;
            int cc = (gi + c) - 3 * B;
            s[B * 4 + cc] = (&v0.x)[c];
        }
        if (h2) {
            int gj = 4 * (tid + 256);
#pragma unroll
            for (int c = 0; c < 4; ++c) {
                int B  = (gj + c) / 3;
                int cc = (gj + c) - 3 * B;
                s[B * 4 + cc] = (&v1.x)[c];
            }
        }
    }
    __syncthreads();

    // ---- distances: 1 frame per iter (5 independent pairs in flight) ----
#pragma unroll 1
    for (int f = 0; f < FPB; ++f) {
        const float4* sf4 = (const float4*)s + f * N_BEADS;
        float* fout = out + (size_t)(f0 + f) * OUT_STRIDE;
#pragma unroll
        for (int k = 0; k < 4; ++k) {   // p = tid + k*256 < 1024 < N_DIST always
            float4 bi = sf4[bi_idx[k]];
            float4 bj = sf4[bj_idx[k]];
            float dx = bj.x - bi.x;
            float dy = bj.y - bi.y;
            float dz = bj.z - bi.z;
            fout[tid + k * 256] = fsqrt_fast(dx * dx + dy * dy + dz * dz);
        }
        if (has_tail) {
            float4 bi = sf4[bi_idx[4]];
            float4 bj = sf4[bj_idx[4]];
            float dx = bj.x - bi.x;
            float dy = bj.y - bi.y;
            float dz = bj.z - bi.z;
            fout[tid + 1024] = fsqrt_fast(dx * dx + dy * dy + dz * dz);
        }
    }

    // ---- angles: 8 frames x 48 = 384 items ----
#pragma unroll 1
    for (int idx = tid; idx < FPB * N_ANG; idx += 256) {
        int f = idx / N_ANG;
        int a = idx - f * N_ANG;
        const float4* sf4 = (const float4*)s + f * N_BEADS;
        float4 A = sf4[a], B = sf4[a + 1], C = sf4[a + 2];
        float b1x = A.x - B.x, b1y = A.y - B.y, b1z = A.z - B.z;
        float b2x = C.x - B.x, b2y = C.y - B.y, b2z = C.z - B.z;
        float dot = b1x * b2x + b1y * b2y + b1z * b2z;
        float s1 = b1x * b1x + b1y * b1y + b1z * b1z;
        float s2 = b2x * b2x + b2y * b2y + b2z * b2z;
        float c = dot * frsq_fast(s1 * s2);
        c = fminf(1.0f, fmaxf(-1.0f, c));
        out[(size_t)(f0 + f) * OUT_STRIDE + N_DIST + a] = acosf(c);
    }

    // ---- dihedrals: 8 frames x 47 = 376 items ----
#pragma unroll 1
    for (int idx = tid; idx < FPB * N_DIH; idx += 256) {
        int f = idx / N_DIH;
        int d = idx - f * N_DIH;
        const float4* sf4 = (const float4*)s + f * N_BEADS;
        float4 P0 = sf4[d], P1 = sf4[d + 1], P2 = sf4[d + 2], P3 = sf4[d + 3];

        float ax = P1.x - P0.x, ay = P1.y - P0.y, az = P1.z - P0.z;
        float bx = P2.x - P1.x, by = P2.y - P1.y, bz = P2.z - P1.z;
        float cx = P3.x - P2.x, cy = P3.y - P2.y, cz = P3.z - P2.z;

        // p1 = a x b ; p2 = b x c
        float p1x = ay * bz - az * by;
        float p1y = az * bx - ax * bz;
        float p1z = ax * by - ay * bx;
        float p2x = by * cz - bz * cy;
        float p2y = bz * cx - bx * cz;
        float p2z = bx * cy - by * cx;

        float s1 = p1x * p1x + p1y * p1y + p1z * p1z;
        float s2 = p2x * p2x + p2y * p2y + p2z * p2z;
        float sb = bx * bx + by * by + bz * bz;

        float dotp = p1x * p2x + p1y * p2y + p1z * p2z;
        // (p1 x p2) . b
        float qx = p1y * p2z - p1z * p2y;
        float qy = p1z * p2x - p1x * p2z;
        float qz = p1x * p2y - p1y * p2x;
        float trip = qx * bx + qy * by + qz * bz;

        float inv12 = frsq_fast(s1 * s2);
        float invb  = frsq_fast(sb);
        size_t base = (size_t)(f0 + f) * OUT_STRIDE + N_DIST + N_ANG;
        out[base + d]         = dotp * inv12;
        out[base + N_DIH + d] = trip * inv12 * invb;
    }
}

extern "C" void kernel_launch(void* const* d_in, const int* in_sizes, int n_in,
                              void* d_out, int out_size, void* d_ws, size_t ws_size,
                              hipStream_t stream) {
    const float* data = (const float*)d_in[0];
    float* out = (float*)d_out;
    protein_feat_kernel<<<N_FRAMES / FPB, 256, 0, stream>>>(data, out);
}